// Round 9
// baseline (233.219 us; speedup 1.0000x reference)
//
#include <hip/hip_runtime.h>
#include <hip/hip_bf16.h>

// CRF NLL + argmax, B=2048, T=1024, K=8.
// p_t = D_t E^T p_{t-1};  E = exp(transitions), computed per-wave -> SGPRs.
// Round-8 structure:
//  - FUSED kernel: blocks [0,4096) = chunk role (4 waves = 32 chunks of ONE
//    shuffled batch; 8-lane group per chunk, lane k = column k; even-split
//    bounds) AND gold-path numerator fused into the score stream (lane k==0
//    per group: blk-of-4 tag prefetch, cndmask emission select, batched
//    trans gathers). Blocks [4096,6144) = pred role: pure argmax stream of
//    log_p (no score/tags traffic -> program reads score exactly once).
//    HW dispatcher backfills single-batch chunk blocks (r7 lesson: no atomic
//    queue; shuffled batch order decorrelates lengths).
//  - combine: block-per-batch LDS tree (6 levels of scale-aware 8x8
//    products), unchanged from r6/r7 (verified absmax 0).

namespace {

constexpr int B = 2048;
constexpr int T = 1024;
constexpr int NC = 64;                      // chunks per batch
constexpr int CHUNK_BLOCKS = B * 2;         // 2 blocks/batch * 4 waves * 8 grp
constexpr int PRED_BLOCKS = (B * T / 4) / 256;  // 2048

__device__ __forceinline__ float max8(const float* a) {
  return fmaxf(fmaxf(fmaxf(a[0], a[1]), fmaxf(a[2], a[3])),
               fmaxf(fmaxf(a[4], a[5]), fmaxf(a[6], a[7])));
}

__device__ __forceinline__ float uniform_f(float v) {
  return __int_as_float(__builtin_amdgcn_readfirstlane(__float_as_int(v)));
}

// select element idx (0..7) from {A.xyzw, B.xyzw} via cndmask chain
__device__ __forceinline__ float sel8(float4 A, float4 B, int idx) {
  float lo = (idx & 1) ? ((idx & 2) ? A.w : A.y) : ((idx & 2) ? A.z : A.x);
  float hi = (idx & 1) ? ((idx & 2) ? B.w : B.y) : ((idx & 2) ? B.z : B.x);
  return (idx & 4) ? hi : lo;
}

// ---------------------------------------------------------------------------
// Fused kernel: chunk+numerator role (bid < CHUNK_BLOCKS) | pred role (else).
// ---------------------------------------------------------------------------
__global__ __launch_bounds__(256) void fused_kernel(
    const float* __restrict__ log_p, const float* __restrict__ score,
    const float* __restrict__ trans, const float* __restrict__ start_tr,
    const float* __restrict__ end_tr, const int* __restrict__ tags,
    const int* __restrict__ seq_l, float* __restrict__ out_pred,
    float* __restrict__ ws_num, float* __restrict__ wsA,
    float* __restrict__ wsS) {
  int bid = blockIdx.x;
  if (bid < CHUNK_BLOCKS) {
    // ----------------------- chunk + numerator role -----------------------
    int braw = bid >> 1;
    int half = bid & 1;
    int b = (int)(((unsigned)braw * 1229u) & 2047u);  // shuffled batch
    int wave = threadIdx.x >> 6;
    int lane = threadIdx.x & 63;
    int grp = lane >> 3;
    int k = lane & 7;
    int c = (half * 4 + wave) * 8 + grp;

    float E[64];
#pragma unroll
    for (int i = 0; i < 64; ++i) E[i] = uniform_f(__expf(trans[i]));

    int L = seq_l[b];
    int S = L - 1;
    int ts = 1 + ((S * c) >> 6);
    int te = 1 + ((S * (c + 1)) >> 6);
    int n = te - ts;

    float a[8];
#pragma unroll
    for (int j = 0; j < 8; ++j) a[j] = (j == k) ? 1.0f : 0.0f;
    float sig = 0.0f;

    const float* sp = score + ((size_t)b * T + ts) * 8;
    const int* tprow = tags + (size_t)b * T;

    // gold-path state (lane k==0 of each group)
    float num = 0.0f;
    int prev = 0, tc0 = 0, tc1 = 0, tc2 = 0, tc3 = 0;
    if (k == 0) {
      if (c == 0) {  // t=0 emission + start transition
        int tg0 = tprow[0];
        num += score[(size_t)b * T * 8 + tg0] + start_tr[tg0];
      }
      if (n > 0) {
        prev = tprow[ts - 1];
        tc0 = tprow[min(ts + 0, T - 1)];
        tc1 = tprow[min(ts + 1, T - 1)];
        tc2 = tprow[min(ts + 2, T - 1)];
        tc3 = tprow[min(ts + 3, T - 1)];
      }
    }

    int nblk = (n + 3) >> 2;
    float4 nA, nB;
    if (n > 0) {
      nA = *reinterpret_cast<const float4*>(sp);
      nB = *reinterpret_cast<const float4*>(sp + 4);
    }
    int t = ts;
    int done = 0;
    for (int blk = 0; blk < nblk; ++blk) {
      int rem = n - done;  // 1..; use up to 4
      int nt0 = 0, nt1 = 0, nt2 = 0, nt3 = 0;
      float tr0 = 0.0f, tr1 = 0.0f, tr2 = 0.0f, tr3 = 0.0f;
      if (k == 0) {
        if (blk + 1 < nblk) {  // prefetch next blk's tags
          nt0 = tprow[min(t + 4, T - 1)];
          nt1 = tprow[min(t + 5, T - 1)];
          nt2 = tprow[min(t + 6, T - 1)];
          nt3 = tprow[min(t + 7, T - 1)];
        }
        // trans gathers for this blk (addresses all known now)
        tr0 = trans[prev * 8 + tc0];
        if (rem > 1) tr1 = trans[tc0 * 8 + tc1];
        if (rem > 2) tr2 = trans[tc1 * 8 + tc2];
        if (rem > 3) tr3 = trans[tc2 * 8 + tc3];
      }
#pragma unroll
      for (int s = 0; s < 4; ++s) {
        if (s >= rem) break;
        float4 cA = nA, cB = nB;
        if (done + s + 1 < n) {  // per-step emission prefetch
          nA = *reinterpret_cast<const float4*>(sp + 8);
          nB = *reinterpret_cast<const float4*>(sp + 12);
        }
        sp += 8;
        if (k == 0) {  // gold emission from RAW scores
          int tgs = (s == 0) ? tc0 : (s == 1) ? tc1 : (s == 2) ? tc2 : tc3;
          num += sel8(cA, cB, tgs);
        }
        float em[8] = {__expf(cA.x), __expf(cA.y), __expf(cA.z), __expf(cA.w),
                       __expf(cB.x), __expf(cB.y), __expf(cB.z), __expf(cB.w)};
        float na[8];
#pragma unroll
        for (int j = 0; j < 8; ++j) {
          float acc = E[0 * 8 + j] * a[0];
#pragma unroll
          for (int i = 1; i < 8; ++i) acc = fmaf(E[i * 8 + j], a[i], acc);
          na[j] = em[j] * acc;
        }
#pragma unroll
        for (int j = 0; j < 8; ++j) a[j] = na[j];
      }
      if (k == 0) {
        num += tr0 + tr1 + tr2 + tr3;
        prev = (rem > 3) ? tc3 : (rem == 3) ? tc2 : (rem == 2) ? tc1 : tc0;
        tc0 = nt0; tc1 = nt1; tc2 = nt2; tc3 = nt3;
      }
      if (blk & 1) {  // rescale every 8 steps
        float mm = max8(a);
        float r = __builtin_amdgcn_rcpf(mm);
#pragma unroll
        for (int j = 0; j < 8; ++j) a[j] *= r;
        sig += __logf(mm);
      }
      done += 4;
      t += 4;
    }
    {  // final normalize (n==0 -> identity, mm==1, sig==0)
      float mm = max8(a);
      if (mm > 0.0f) {
        float r = __builtin_amdgcn_rcpf(mm);
#pragma unroll
        for (int j = 0; j < 8; ++j) a[j] *= r;
        sig += __logf(mm);
      }
    }
    if (k == 0 && c == NC - 1) {  // end transition: te == L here
      num += end_tr[tprow[te - 1]];
    }

    float* Ao = wsA + (size_t)(b * NC + c) * 64;
#pragma unroll
    for (int j = 0; j < 8; ++j) Ao[j * 8 + k] = a[j];  // row-major
    wsS[(b * NC + c) * 8 + k] = sig;

    // wave-reduce numerator partials (k!=0 lanes contribute 0)
    float part = (k == 0) ? num : 0.0f;
#pragma unroll
    for (int off = 32; off >= 1; off >>= 1) part += __shfl_down(part, off);
    if (lane == 0) atomicAdd(&ws_num[b], part);
  } else {
    // ----------------------------- pred role ------------------------------
    int tid = (bid - CHUNK_BLOCKS) * 256 + threadIdx.x;
    int g0 = tid << 2;
    int b = g0 >> 10;
    int t0 = g0 & (T - 1);
    int L = seq_l[b];

    const float4* lp = reinterpret_cast<const float4*>(log_p) + (g0 << 1);
    float4 u[8];
#pragma unroll
    for (int r = 0; r < 8; ++r) u[r] = lp[r];
#pragma unroll
    for (int r = 0; r < 4; ++r) {
      float v[8] = {u[2 * r].x, u[2 * r].y, u[2 * r].z, u[2 * r].w,
                    u[2 * r + 1].x, u[2 * r + 1].y, u[2 * r + 1].z,
                    u[2 * r + 1].w};
      int best = 0;
      float bv = v[0];
#pragma unroll
      for (int j = 1; j < 8; ++j) {
        if (v[j] > bv) { bv = v[j]; best = j; }  // first max == jnp.argmax
      }
      out_pred[g0 + r] = (t0 + r < L) ? (float)best : 0.0f;
    }
  }
}

// ---------------------------------------------------------------------------
// Combine — block per batch, LDS tree of scale-aware products (r6, verified).
// ---------------------------------------------------------------------------
__global__ __launch_bounds__(256) void combine_kernel(
    const float* __restrict__ score, const float* __restrict__ start_tr,
    const float* __restrict__ end_tr, const float* __restrict__ wsA,
    const float* __restrict__ wsS, const float* __restrict__ ws_num,
    float* __restrict__ out_loss) {
  __shared__ float sm[96 * 73];
  int b = blockIdx.x;
  int tid = threadIdx.x;
  const float* Ab = wsA + (size_t)b * NC * 64;
  const float* Sb = wsS + (size_t)b * NC * 8;

#pragma unroll
  for (int r = 0; r < 4; ++r) {
    int vi = tid + r * 256;
    int g = vi * 4;
    int c = g >> 6, rem = g & 63;
    float4 q = reinterpret_cast<const float4*>(Ab)[vi];
    float* dst = &sm[c * 73 + rem];
    dst[0] = q.x; dst[1] = q.y; dst[2] = q.z; dst[3] = q.w;
  }
#pragma unroll
  for (int r = 0; r < 2; ++r) {
    int gi = tid + r * 256;
    sm[(gi >> 3) * 73 + 64 + (gi & 7)] = Sb[gi];
  }
  __syncthreads();

  float* bufB = &sm[64 * 73];
  int p = tid >> 3, k = tid & 7;
#pragma unroll
  for (int lvl = 1; lvl <= 6; ++lvl) {
    int nprod = NC >> lvl;
    float* inb = (lvl & 1) ? sm : bufB;
    float* outb = (lvl & 1) ? bufB : sm;
    if (p < nprod) {
      const float* M0 = inb + (size_t)(2 * p) * 73;      // earlier (right)
      const float* M1 = inb + (size_t)(2 * p + 1) * 73;  // later (left)
      float s1[8];
#pragma unroll
      for (int i = 0; i < 8; ++i) s1[i] = M1[64 + i];
      float m = max8(s1);
      float w[8];
#pragma unroll
      for (int i = 0; i < 8; ++i) w[i] = M0[i * 8 + k] * __expf(s1[i] - m);
      float u[8];
#pragma unroll
      for (int j = 0; j < 8; ++j) {
        float acc = M1[j * 8 + 0] * w[0];
#pragma unroll
        for (int i = 1; i < 8; ++i) acc = fmaf(M1[j * 8 + i], w[i], acc);
        u[j] = acc;
      }
      float mm = fmaxf(max8(u), 1e-37f);
      float rc = __builtin_amdgcn_rcpf(mm);
      float* D = outb + (size_t)p * 73;
#pragma unroll
      for (int j = 0; j < 8; ++j) D[j * 8 + k] = u[j] * rc;
      D[64 + k] = M0[64 + k] + m + __logf(mm);
    }
    __syncthreads();
  }

  if (tid < 8) {
    int j = tid;
    float p0 = __expf(start_tr[j] + score[(size_t)b * T * 8 + j]);
    float m0 = p0;
#pragma unroll
    for (int m = 1; m < 8; m <<= 1) m0 = fmaxf(m0, __shfl_xor(m0, m, 8));
    float p0n = p0 * __builtin_amdgcn_rcpf(m0);
    float p0a[8];
#pragma unroll
    for (int i = 0; i < 8; ++i) p0a[i] = __shfl(p0n, i, 8);
    float sM[8];
#pragma unroll
    for (int i = 0; i < 8; ++i) sM[i] = sm[64 + i];
    float mS = max8(sM);
    float inner = 0.0f;
#pragma unroll
    for (int i = 0; i < 8; ++i)
      inner = fmaf(sm[j * 8 + i], __expf(sM[i] - mS) * p0a[i], inner);
    float term = inner * __expf(end_tr[j]);
#pragma unroll
    for (int m = 1; m < 8; m <<= 1) term += __shfl_xor(term, m, 8);
    if (j == 0) {
      float logz = __logf(m0) + mS + __logf(term);
      atomicAdd(out_loss, (logz - ws_num[b]) * (1.0f / (float)B));
    }
  }
}

}  // namespace

extern "C" void kernel_launch(void* const* d_in, const int* in_sizes, int n_in,
                              void* d_out, int out_size, void* d_ws,
                              size_t ws_size, hipStream_t stream) {
  const float* log_p = (const float*)d_in[0];
  const float* score = (const float*)d_in[1];
  const float* trans = (const float*)d_in[2];
  const float* start_tr = (const float*)d_in[3];
  const float* end_tr = (const float*)d_in[4];
  const int* tags = (const int*)d_in[5];
  const int* seq_l = (const int*)d_in[6];
  float* out = (float*)d_out;  // out[0]=loss, out[1..]=pred_idx

  float* wsA = (float*)d_ws;                // B*NC*64
  float* wsS = wsA + (size_t)B * NC * 64;   // B*NC*8
  float* wsNum = wsS + (size_t)B * NC * 8;  // B

  hipMemsetAsync(wsNum, 0, B * sizeof(float), stream);
  hipMemsetAsync(out, 0, sizeof(float), stream);

  fused_kernel<<<CHUNK_BLOCKS + PRED_BLOCKS, 256, 0, stream>>>(
      log_p, score, trans, start_tr, end_tr, tags, seq_l, out + 1, wsNum,
      wsA, wsS);
  combine_kernel<<<B, 256, 0, stream>>>(score, start_tr, end_tr, wsA, wsS,
                                        wsNum, out);
}